// Round 2
// baseline (18627.434 us; speedup 1.0000x reference)
//
#include <hip/hip_runtime.h>
#include <stdint.h>
#include <math.h>

// Problem constants (match reference)
#define BB 128
#define NN 2048
#define DD 2
#define ROWLEN (2 + NN * DD + 5)   // 4103
#define SIGMA_C 0.001f
#define HALF_CNT 262144u           // B*N*D / 2

__device__ __forceinline__ uint32_t rotl32(uint32_t v, uint32_t r) {
  return (v << r) | (v >> (32u - r));
}

// JAX threefry2x32 (20 rounds), matches jax/_src/prng.py
__device__ __forceinline__ void tf2x32(uint32_t k0, uint32_t k1,
                                       uint32_t x0, uint32_t x1,
                                       uint32_t& o0, uint32_t& o1) {
  uint32_t k2 = k0 ^ k1 ^ 0x1BD11BDAu;
  x0 += k0; x1 += k1;
#define TF_R(r) { x0 += x1; x1 = rotl32(x1, r); x1 ^= x0; }
  TF_R(13) TF_R(15) TF_R(26) TF_R(6)   x0 += k1; x1 += k2 + 1u;
  TF_R(17) TF_R(29) TF_R(16) TF_R(24)  x0 += k2; x1 += k0 + 2u;
  TF_R(13) TF_R(15) TF_R(26) TF_R(6)   x0 += k0; x1 += k1 + 3u;
  TF_R(17) TF_R(29) TF_R(16) TF_R(24)  x0 += k1; x1 += k2 + 4u;
  TF_R(13) TF_R(15) TF_R(26) TF_R(6)   x0 += k2; x1 += k0 + 5u;
#undef TF_R
  o0 = x0; o1 = x1;
}

// XLA f32 ErfInv (Giles 2012 polynomial) — what lax.erf_inv lowers to
__device__ __forceinline__ float erfinv_f32(float x) {
  float w = -log1pf(-(x * x));
  float p;
  if (w < 5.0f) {
    w = w - 2.5f;
    p = 2.81022636e-08f;
    p = fmaf(p, w, 3.43273939e-07f);
    p = fmaf(p, w, -3.5233877e-06f);
    p = fmaf(p, w, -4.39150654e-06f);
    p = fmaf(p, w, 0.00021858087f);
    p = fmaf(p, w, -0.00125372503f);
    p = fmaf(p, w, -0.00417768164f);
    p = fmaf(p, w, 0.246640727f);
    p = fmaf(p, w, 1.50140941f);
  } else {
    w = sqrtf(w) - 3.0f;
    p = -0.000200214257f;
    p = fmaf(p, w, 0.000100950558f);
    p = fmaf(p, w, 0.00134934322f);
    p = fmaf(p, w, -0.00367342844f);
    p = fmaf(p, w, 0.00573950773f);
    p = fmaf(p, w, -0.0076224613f);
    p = fmaf(p, w, 0.00943887047f);
    p = fmaf(p, w, 1.00167406f);
    p = fmaf(p, w, 2.83297682f);
  }
  return p * x;
}

// jax.random.normal for one flat element index f under key (k0,k1)
__device__ __forceinline__ float jax_normal_elem(uint32_t k0, uint32_t k1,
                                                 uint32_t f) {
  uint32_t o0, o1, bits;
  if (f < HALF_CNT) {
    tf2x32(k0, k1, f, f + HALF_CNT, o0, o1);
    bits = o0;
  } else {
    tf2x32(k0, k1, f - HALF_CNT, f, o0, o1);
    bits = o1;
  }
  float u01 = __uint_as_float((bits >> 9) | 0x3f800000u) - 1.0f;
  const float lo = -0.99999994f;           // nextafter(-1, 0) in f32
  float v = fmaxf(lo, fmaf(u01, 2.0f, lo));
  return 1.41421356237309515f * erfinv_f32(v);
}

// amdgpu_waves_per_eu(2,2): pin the register allocator's occupancy target to
// exactly 2 waves/SIMD -> 256-VGPR budget. R1 showed __launch_bounds__(256,2)
// alone lets the allocator target ~5 waves/EU (92 VGPRs) and spill the
// activation arrays to scratch (350 MB WRITE_SIZE, 1.1 GB FETCH_SIZE).
__global__ __attribute__((amdgpu_flat_work_group_size(256, 256),
                          amdgpu_waves_per_eu(2, 2)))
void phinn_kernel(
    const float* __restrict__ x,
    const float* __restrict__ W1, const float* __restrict__ b1,
    const float* __restrict__ W2, const float* __restrict__ b2,
    const float* __restrict__ W3, const float* __restrict__ b3,
    const float* __restrict__ W4, const float* __restrict__ b4,
    const float* __restrict__ W5, const float* __restrict__ b5,
    const float* __restrict__ Wt,
    const float* __restrict__ dtp, const int* __restrict__ nstepsp,
    float* __restrict__ out) {
  const int tid = blockIdx.x * 256 + threadIdx.x;   // 0 .. B*N-1
  const int bidx = tid >> 11;                        // / N
  const int nidx = tid & (NN - 1);

  const float dt = dtp[0];
  const int nsteps = nstepsp[0];
  const float sqdt = sqrtf(dt);

  const float* xr = x + (size_t)bidx * ROWLEN;
  float t = xr[0];
  float y0 = xr[2 + nidx * 2 + 0];
  float y1 = xr[2 + nidx * 2 + 1];
  const float tcrit = xr[2 + NN * DD + 0];
  const float sp0 = xr[2 + NN * DD + 1];
  const float sp1 = xr[2 + NN * DD + 2];
  const float sq0 = xr[2 + NN * DD + 3];
  const float sq1 = xr[2 + NN * DD + 4];

  // Wt is (D, NSIG) row-major; tilt[d] = sum_s signals[s] * Wt[d][s]
  const float wt00 = Wt[0], wt01 = Wt[1], wt10 = Wt[2], wt11 = Wt[3];

  const uint32_t f0 = (uint32_t)(tid << 1);  // flat idx of component 0

  for (int i = 0; i < nsteps; ++i) {
    // per-step key: fold_in(key(42), i) = threefry((0,42), (0,i))
    uint32_t k0, k1;
    tf2x32(0u, 42u, 0u, (uint32_t)i, k0, k1);

    // ---- forward: 2 -> 16 -> 32 -> 32 -> 16 -> 1 ----
    float h1[16], d1[16];
#pragma unroll
    for (int j = 0; j < 16; ++j) {
      float z = fmaf(W1[2 * j + 0], y0, fmaf(W1[2 * j + 1], y1, b1[j]));
      float ex = __expf(z);
      h1[j] = z > 0.0f ? z : (ex - 1.0f);
      d1[j] = z > 0.0f ? 1.0f : ex;
    }
    float h2[32], d2[32];
#pragma unroll
    for (int j = 0; j < 32; ++j) {
      float z = b2[j];
#pragma unroll
      for (int k = 0; k < 16; ++k) z = fmaf(W2[16 * j + k], h1[k], z);
      float ex = __expf(z);
      h2[j] = z > 0.0f ? z : (ex - 1.0f);
      d2[j] = z > 0.0f ? 1.0f : ex;
    }
    float h3[32], d3[32];
#pragma unroll
    for (int j = 0; j < 32; ++j) {
      float z = b3[j];
#pragma unroll
      for (int k = 0; k < 32; ++k) z = fmaf(W3[32 * j + k], h2[k], z);
      float ex = __expf(z);
      h3[j] = z > 0.0f ? z : (ex - 1.0f);
      d3[j] = z > 0.0f ? 1.0f : ex;
    }
    float h4[16], d4[16];
#pragma unroll
    for (int j = 0; j < 16; ++j) {
      float z = b4[j];
#pragma unroll
      for (int k = 0; k < 32; ++k) z = fmaf(W4[32 * j + k], h3[k], z);
      float ex = __expf(z);
      h4[j] = z > 0.0f ? z : (ex - 1.0f);
      d4[j] = z > 0.0f ? 1.0f : ex;
    }
    float z5 = b5[0];
#pragma unroll
    for (int k = 0; k < 16; ++k) z5 = fmaf(W5[k], h4[k], z5);
    // d softplus = sigmoid
    float g5 = 1.0f / (1.0f + __expf(-z5));

    // ---- backward (input-gradient) ----
    float g4[16];
#pragma unroll
    for (int k = 0; k < 16; ++k) g4[k] = W5[k] * g5 * d4[k];
    float g3[32];
#pragma unroll
    for (int k = 0; k < 32; ++k) {
      float s = 0.0f;
#pragma unroll
      for (int j = 0; j < 16; ++j) s = fmaf(W4[32 * j + k], g4[j], s);
      g3[k] = s * d3[k];
    }
    float g2[32];
#pragma unroll
    for (int k = 0; k < 32; ++k) {
      float s = 0.0f;
#pragma unroll
      for (int j = 0; j < 32; ++j) s = fmaf(W3[32 * j + k], g3[j], s);
      g2[k] = s * d2[k];
    }
    float g1[16];
#pragma unroll
    for (int k = 0; k < 16; ++k) {
      float s = 0.0f;
#pragma unroll
      for (int j = 0; j < 32; ++j) s = fmaf(W2[16 * j + k], g2[j], s);
      g1[k] = s * d1[k];
    }
    float gy0 = 0.0f, gy1 = 0.0f;
#pragma unroll
    for (int j = 0; j < 16; ++j) {
      gy0 = fmaf(W1[2 * j + 0], g1[j], gy0);
      gy1 = fmaf(W1[2 * j + 1], g1[j], gy1);
    }

    // ---- tilt ----
    bool pre = t < tcrit;
    float s0 = pre ? sp0 : sq0;
    float s1 = pre ? sp1 : sq1;
    float tilt0 = fmaf(s0, wt00, s1 * wt01);
    float tilt1 = fmaf(s0, wt10, s1 * wt11);

    // ---- noise (exact JAX threefry normal) ----
    float nz0 = jax_normal_elem(k0, k1, f0);
    float nz1 = jax_normal_elem(k0, k1, f0 + 1u);

    // ---- Euler-Maruyama update ----
    float drift0 = -(gy0 + tilt0);
    float drift1 = -(gy1 + tilt1);
    y0 = y0 + drift0 * dt + SIGMA_C * (nz0 * sqdt);
    y1 = y1 + drift1 * dt + SIGMA_C * (nz1 * sqdt);
    t += dt;
  }

  out[(size_t)tid * 2 + 0] = y0;
  out[(size_t)tid * 2 + 1] = y1;
}

extern "C" void kernel_launch(void* const* d_in, const int* in_sizes, int n_in,
                              void* d_out, int out_size, void* d_ws,
                              size_t ws_size, hipStream_t stream) {
  const float* x  = (const float*)d_in[0];
  const float* W1 = (const float*)d_in[1];
  const float* b1 = (const float*)d_in[2];
  const float* W2 = (const float*)d_in[3];
  const float* b2 = (const float*)d_in[4];
  const float* W3 = (const float*)d_in[5];
  const float* b3 = (const float*)d_in[6];
  const float* W4 = (const float*)d_in[7];
  const float* b4 = (const float*)d_in[8];
  const float* W5 = (const float*)d_in[9];
  const float* b5 = (const float*)d_in[10];
  const float* Wt = (const float*)d_in[11];
  const float* dt = (const float*)d_in[12];
  const int* nsteps = (const int*)d_in[13];
  float* out = (float*)d_out;

  dim3 grid((BB * NN) / 256);
  dim3 block(256);
  hipLaunchKernelGGL(phinn_kernel, grid, block, 0, stream,
                     x, W1, b1, W2, b2, W3, b3, W4, b4, W5, b5, Wt, dt, nsteps,
                     out);
}

// Round 3
// 8863.418 us; speedup vs baseline: 2.1016x; 2.1016x over previous
//
#include <hip/hip_runtime.h>
#include <stdint.h>
#include <math.h>

// Problem constants (match reference)
#define BB 128
#define NN 2048
#define DD 2
#define ROWLEN (2 + NN * DD + 5)   // 4103
#define SIGMA_C 0.001f
#define HALF_CNT 262144u           // B*N*D / 2

// SSA vector types: subscripting lowers to insert/extractelement (never an
// alloca). R1/R2 showed float arrays stay in scratch memory (VGPR=92,
// ~290 MB/launch of scratch spill traffic to HBM) regardless of occupancy
// attributes — the arrays were never promoted. Vectors force VGPR residency.
typedef float v16f __attribute__((ext_vector_type(16)));
typedef float v32f __attribute__((ext_vector_type(32)));

// elu derivative from elu output: d = (z>0) ? 1 : exp(z); and for z<=0,
// h = exp(z)-1  =>  d = h+1 (<=1 ulp difference). h>0 <=> z>0 (monotone).
#define DFROMH(h) ((h) > 0.0f ? 1.0f : (h) + 1.0f)

__device__ __forceinline__ uint32_t rotl32(uint32_t v, uint32_t r) {
  return (v << r) | (v >> (32u - r));
}

// JAX threefry2x32 (20 rounds), matches jax/_src/prng.py
__device__ __forceinline__ void tf2x32(uint32_t k0, uint32_t k1,
                                       uint32_t x0, uint32_t x1,
                                       uint32_t& o0, uint32_t& o1) {
  uint32_t k2 = k0 ^ k1 ^ 0x1BD11BDAu;
  x0 += k0; x1 += k1;
#define TF_R(r) { x0 += x1; x1 = rotl32(x1, r); x1 ^= x0; }
  TF_R(13) TF_R(15) TF_R(26) TF_R(6)   x0 += k1; x1 += k2 + 1u;
  TF_R(17) TF_R(29) TF_R(16) TF_R(24)  x0 += k2; x1 += k0 + 2u;
  TF_R(13) TF_R(15) TF_R(26) TF_R(6)   x0 += k0; x1 += k1 + 3u;
  TF_R(17) TF_R(29) TF_R(16) TF_R(24)  x0 += k1; x1 += k2 + 4u;
  TF_R(13) TF_R(15) TF_R(26) TF_R(6)   x0 += k2; x1 += k0 + 5u;
#undef TF_R
  o0 = x0; o1 = x1;
}

// XLA f32 ErfInv (Giles 2012 polynomial) — what lax.erf_inv lowers to
__device__ __forceinline__ float erfinv_f32(float x) {
  float w = -log1pf(-(x * x));
  float p;
  if (w < 5.0f) {
    w = w - 2.5f;
    p = 2.81022636e-08f;
    p = fmaf(p, w, 3.43273939e-07f);
    p = fmaf(p, w, -3.5233877e-06f);
    p = fmaf(p, w, -4.39150654e-06f);
    p = fmaf(p, w, 0.00021858087f);
    p = fmaf(p, w, -0.00125372503f);
    p = fmaf(p, w, -0.00417768164f);
    p = fmaf(p, w, 0.246640727f);
    p = fmaf(p, w, 1.50140941f);
  } else {
    w = sqrtf(w) - 3.0f;
    p = -0.000200214257f;
    p = fmaf(p, w, 0.000100950558f);
    p = fmaf(p, w, 0.00134934322f);
    p = fmaf(p, w, -0.00367342844f);
    p = fmaf(p, w, 0.00573950773f);
    p = fmaf(p, w, -0.0076224613f);
    p = fmaf(p, w, 0.00943887047f);
    p = fmaf(p, w, 1.00167406f);
    p = fmaf(p, w, 2.83297682f);
  }
  return p * x;
}

// jax.random.normal for one flat element index f under key (k0,k1)
__device__ __forceinline__ float jax_normal_elem(uint32_t k0, uint32_t k1,
                                                 uint32_t f) {
  uint32_t o0, o1, bits;
  if (f < HALF_CNT) {
    tf2x32(k0, k1, f, f + HALF_CNT, o0, o1);
    bits = o0;
  } else {
    tf2x32(k0, k1, f - HALF_CNT, f, o0, o1);
    bits = o1;
  }
  float u01 = __uint_as_float((bits >> 9) | 0x3f800000u) - 1.0f;
  const float lo = -0.99999994f;           // nextafter(-1, 0) in f32
  float v = fmaxf(lo, fmaf(u01, 2.0f, lo));
  return 1.41421356237309515f * erfinv_f32(v);
}

__global__ __launch_bounds__(256, 2) void phinn_kernel(
    const float* __restrict__ x,
    const float* __restrict__ W1, const float* __restrict__ b1,
    const float* __restrict__ W2, const float* __restrict__ b2,
    const float* __restrict__ W3, const float* __restrict__ b3,
    const float* __restrict__ W4, const float* __restrict__ b4,
    const float* __restrict__ W5, const float* __restrict__ b5,
    const float* __restrict__ Wt,
    const float* __restrict__ dtp, const int* __restrict__ nstepsp,
    float* __restrict__ out) {
  const int tid = blockIdx.x * 256 + threadIdx.x;   // 0 .. B*N-1
  const int bidx = tid >> 11;                        // / N
  const int nidx = tid & (NN - 1);

  const float dt = dtp[0];
  const int nsteps = nstepsp[0];
  const float sqdt = sqrtf(dt);

  const float* xr = x + (size_t)bidx * ROWLEN;
  float t = xr[0];
  float y0 = xr[2 + nidx * 2 + 0];
  float y1 = xr[2 + nidx * 2 + 1];
  const float tcrit = xr[2 + NN * DD + 0];
  const float sp0 = xr[2 + NN * DD + 1];
  const float sp1 = xr[2 + NN * DD + 2];
  const float sq0 = xr[2 + NN * DD + 3];
  const float sq1 = xr[2 + NN * DD + 4];

  // Wt is (D, NSIG) row-major; tilt[d] = sum_s signals[s] * Wt[d][s]
  const float wt00 = Wt[0], wt01 = Wt[1], wt10 = Wt[2], wt11 = Wt[3];

  const uint32_t f0 = (uint32_t)(tid << 1);  // flat idx of component 0

  for (int i = 0; i < nsteps; ++i) {
    // per-step key: fold_in(key(42), i) = threefry((0,42), (0,i))
    // (uniform across threads -> compiler scalarizes to the SALU pipe)
    uint32_t k0, k1;
    tf2x32(0u, 42u, 0u, (uint32_t)i, k0, k1);

    // ---- forward: 2 -> 16 -> 32 -> 32 -> 16 -> 1 (keep only h, not d) ----
    v16f h1;
#pragma unroll
    for (int j = 0; j < 16; ++j) {
      float z = fmaf(W1[2 * j + 0], y0, fmaf(W1[2 * j + 1], y1, b1[j]));
      h1[j] = z > 0.0f ? z : (__expf(z) - 1.0f);
    }
    v32f h2;
#pragma unroll
    for (int j = 0; j < 32; ++j) {
      float z = b2[j];
#pragma unroll
      for (int k = 0; k < 16; ++k) z = fmaf(W2[16 * j + k], h1[k], z);
      h2[j] = z > 0.0f ? z : (__expf(z) - 1.0f);
    }
    v32f h3;
#pragma unroll
    for (int j = 0; j < 32; ++j) {
      float z = b3[j];
#pragma unroll
      for (int k = 0; k < 32; ++k) z = fmaf(W3[32 * j + k], h2[k], z);
      h3[j] = z > 0.0f ? z : (__expf(z) - 1.0f);
    }
    v16f h4;
#pragma unroll
    for (int j = 0; j < 16; ++j) {
      float z = b4[j];
#pragma unroll
      for (int k = 0; k < 32; ++k) z = fmaf(W4[32 * j + k], h3[k], z);
      h4[j] = z > 0.0f ? z : (__expf(z) - 1.0f);
    }
    float z5 = b5[0];
#pragma unroll
    for (int k = 0; k < 16; ++k) z5 = fmaf(W5[k], h4[k], z5);
    // d softplus = sigmoid
    float g5 = 1.0f / (1.0f + __expf(-z5));

    // ---- backward (input-gradient), derivatives recomputed from h ----
    v16f g4;
#pragma unroll
    for (int k = 0; k < 16; ++k) g4[k] = W5[k] * g5 * DFROMH(h4[k]);
    v32f g3;
#pragma unroll
    for (int k = 0; k < 32; ++k) {
      float s = 0.0f;
#pragma unroll
      for (int j = 0; j < 16; ++j) s = fmaf(W4[32 * j + k], g4[j], s);
      g3[k] = s * DFROMH(h3[k]);
    }
    v32f g2;
#pragma unroll
    for (int k = 0; k < 32; ++k) {
      float s = 0.0f;
#pragma unroll
      for (int j = 0; j < 32; ++j) s = fmaf(W3[32 * j + k], g3[j], s);
      g2[k] = s * DFROMH(h2[k]);
    }
    v16f g1;
#pragma unroll
    for (int k = 0; k < 16; ++k) {
      float s = 0.0f;
#pragma unroll
      for (int j = 0; j < 32; ++j) s = fmaf(W2[16 * j + k], g2[j], s);
      g1[k] = s * DFROMH(h1[k]);
    }
    float gy0 = 0.0f, gy1 = 0.0f;
#pragma unroll
    for (int j = 0; j < 16; ++j) {
      gy0 = fmaf(W1[2 * j + 0], g1[j], gy0);
      gy1 = fmaf(W1[2 * j + 1], g1[j], gy1);
    }

    // ---- tilt ----
    bool pre = t < tcrit;
    float s0 = pre ? sp0 : sq0;
    float s1 = pre ? sp1 : sq1;
    float tilt0 = fmaf(s0, wt00, s1 * wt01);
    float tilt1 = fmaf(s0, wt10, s1 * wt11);

    // ---- noise (exact JAX threefry normal) ----
    float nz0 = jax_normal_elem(k0, k1, f0);
    float nz1 = jax_normal_elem(k0, k1, f0 + 1u);

    // ---- Euler-Maruyama update ----
    float drift0 = -(gy0 + tilt0);
    float drift1 = -(gy1 + tilt1);
    y0 = y0 + drift0 * dt + SIGMA_C * (nz0 * sqdt);
    y1 = y1 + drift1 * dt + SIGMA_C * (nz1 * sqdt);
    t += dt;
  }

  out[(size_t)tid * 2 + 0] = y0;
  out[(size_t)tid * 2 + 1] = y1;
}

extern "C" void kernel_launch(void* const* d_in, const int* in_sizes, int n_in,
                              void* d_out, int out_size, void* d_ws,
                              size_t ws_size, hipStream_t stream) {
  const float* x  = (const float*)d_in[0];
  const float* W1 = (const float*)d_in[1];
  const float* b1 = (const float*)d_in[2];
  const float* W2 = (const float*)d_in[3];
  const float* b2 = (const float*)d_in[4];
  const float* W3 = (const float*)d_in[5];
  const float* b3 = (const float*)d_in[6];
  const float* W4 = (const float*)d_in[7];
  const float* b4 = (const float*)d_in[8];
  const float* W5 = (const float*)d_in[9];
  const float* b5 = (const float*)d_in[10];
  const float* Wt = (const float*)d_in[11];
  const float* dt = (const float*)d_in[12];
  const int* nsteps = (const int*)d_in[13];
  float* out = (float*)d_out;

  dim3 grid((BB * NN) / 256);
  dim3 block(256);
  hipLaunchKernelGGL(phinn_kernel, grid, block, 0, stream,
                     x, W1, b1, W2, b2, W3, b3, W4, b4, W5, b5, Wt, dt, nsteps,
                     out);
}